// Round 15
// baseline (2920.118 us; speedup 1.0000x reference)
//
#include <hip/hip_runtime.h>
#include <hip/hip_bf16.h>
#include <stdint.h>

#define BSZ 1024
#define HSZ 512
#define TSZ 48
#define INSZ 64
#define GSZ 2048  // 4*HSZ

typedef __attribute__((ext_vector_type(4))) int i32x4;
typedef __attribute__((ext_vector_type(16))) int i32x16;
typedef __attribute__((ext_vector_type(8))) char char8;

#define GLDS16(g, l)                                                        \
    __builtin_amdgcn_global_load_lds(                                       \
        (const __attribute__((address_space(1))) void*)(g),                 \
        (__attribute__((address_space(3))) void*)(l), 16, 0, 0)

#define SB0 __builtin_amdgcn_sched_barrier(0);
#define WAITV4 asm volatile("s_waitcnt vmcnt(4)" ::: "memory");
#define BARRAW __builtin_amdgcn_s_barrier();

__device__ __forceinline__ float sigmf(float x) { return 1.0f / (1.0f + __expf(-x)); }
__device__ __forceinline__ float tanhf_(float x) { return 2.0f / (1.0f + __expf(-2.0f * x)) - 1.0f; }
__device__ __forceinline__ int clamp13(int q) {
    return q > 8191 ? 8191 : (q < -8191 ? -8191 : q);
}

// ---- i8 fixed-point scheme ----
// A (h, or x/6) in (-1,1): aq = rn(a*8192) 14-bit; ah=(aq+64)>>7, al=aq-(ah<<7).
// W': l0 x-rows pre-multiplied by 6; per-column scale sB; bq = rn(w/sB*8192).
// a.b = sB*2^-26 * (2^14*ACC_hh + 2^7*ACC_x),  ACC_x = sum(ah*bl + al*bh).
// (al*bl dropped, rel err ~2e-4.)
// Layouts (i8, hi/lo separate slabs, 16-elem k-chunks):
//   A: [p=row/64][kc16=k/16][r=row&63][e=16]   W: [np=col'/128][kc16][c=col'&127][e=16]
// col' = hidden*4 + gate. MFMA i32_32x32x32_i8 (K=32, 2x bf16 rate, exact).
// Skeleton = r12: A->LDS dbuf via glds, B->reg dbuf (named sets), counted
// vmcnt(4) + raw barrier (glds completes, B stays in flight).
// grid (16,16,ncells): 64 rows x 128 gate-cols per block, 256 threads.
__global__ __launch_bounds__(256, 3) void lstm_diag(
    const char* __restrict__ xqh, const char* __restrict__ xql,
    char* __restrict__ hq,          // [par][layer][hilo] i8 pk-slabs
    float* __restrict__ Cbuf,       // [layer][B*H] f32
    const char* __restrict__ W0h, const char* __restrict__ W0l,
    const char* __restrict__ W1h, const char* __restrict__ W1l,
    const char* __restrict__ W2h, const char* __restrict__ W2l,
    const float* __restrict__ ws0, const float* __restrict__ ws1,
    const float* __restrict__ ws2,
    const float* __restrict__ b0, const float* __restrict__ b1,
    const float* __restrict__ b2,
    int d, int lmin)
{
    // A dbuf: 2 x (hi 4K | lo 4K) = 16K; epilogue gt 64*132*4 = 33792 (aliased)
    __shared__ __align__(16) char lds[33792];

    const int l = lmin + blockIdx.z;
    const int t = d - l;
    const size_t hsl = (size_t)BSZ * HSZ;  // bytes per i8 h-slab
    auto Hq = [&](int par, int ll, int hilo) {
        return hq + (((size_t)par * 3 + ll) * 2 + hilo) * hsl;
    };

    const char* Wph = (l == 0) ? W0h : (l == 1) ? W1h : W2h;
    const char* Wpl = (l == 0) ? W0l : (l == 1) ? W1l : W2l;
    const float* wsc = (l == 0) ? ws0 : (l == 1) ? ws1 : ws2;
    const float* bias = (l == 0) ? b0 : (l == 1) ? b1 : b2;
    const int Kx    = (l == 0) ? INSZ : HSZ;
    const int KCa16 = Kx >> 4;        // kc16 per panel in x-source slab (4 / 32)
    const int Ktot  = Kx + HSZ;
    const int KCt16 = Ktot >> 4;
    const int nkx   = Kx >> 6;        // ksteps in x phase (1 or 8)
    const int nkt   = Ktot >> 6;      // total ksteps (9 or 16)
    const int cur = t & 1, prv = cur ^ 1;
    const char* Axh = (l == 0) ? xqh + (size_t)t * 65536 : Hq(cur, l - 1, 0);
    const char* Axl = (l == 0) ? xql + (size_t)t * 65536 : Hq(cur, l - 1, 1);
    const char* Ahh = Hq(prv, l, 0);
    const char* Ahl = Hq(prv, l, 1);
    float* C = Cbuf + (size_t)l * BSZ * HSZ;
    char* hhi = Hq(cur, l, 0);
    char* hlo = Hq(cur, l, 1);

    // XCD-aware bijective swizzle within the 256-block z-slice (256 % 8 == 0).
    const int bid = blockIdx.x + (blockIdx.y << 4);
    const int swz = (bid & 7) * 32 + (bid >> 3);
    const int m0 = (swz & 15) * 64;
    const int n0 = (swz >> 4) * 128;
    const int p  = swz & 15;    // A row-panel
    const int np = swz >> 4;    // W col-panel

    const int tid = threadIdx.x;
    const int lane = tid & 63;
    const int wv = tid >> 6;
    const int lrow32 = lane & 31;
    const int lk2 = lane >> 5;

    // A source byte bases (panel-resolved)
    const char* bAxh = Axh + (size_t)p * KCa16 * 1024;
    const char* bAxl = Axl + (size_t)p * KCa16 * 1024;
    const char* bAhh = Ahh + (size_t)p * 32 * 1024;
    const char* bAhl = Ahl + (size_t)p * 32 * 1024;
    // W byte bases (panel-resolved)
    const char* bWhp = Wph + (size_t)np * KCt16 * 2048;
    const char* bWlp = Wpl + (size_t)np * KCt16 * 2048;

    // per-lane offsets
    const int boff = (wv * 32 + lrow32) * 16;   // + kc16*2048
    const int aoff = lrow32 * 16;               // + kc16*1024 (+512 rows 32-63)

    i32x16 acc0h, acc0x, acc1h, acc1x;
#pragma unroll
    for (int r = 0; r < 16; ++r) { acc0h[r] = 0; acc0x[r] = 0; acc1h[r] = 0; acc1x[r] = 0; }

    // stage A kstep ks into buf[ks&1]: 8 x 1KB segments (4 hi + 4 lo), 2/wave
    auto stage = [&](int ks) {
        const char *sh, *sl;
        int kc0;
        if (ks < nkx) { sh = bAxh; sl = bAxl; kc0 = ks * 4; }
        else          { sh = bAhh; sl = bAhl; kc0 = (ks - nkx) * 4; }
        char* dst = lds + (ks & 1) * 8192;
        size_t so = (size_t)(kc0 + wv) * 1024 + lane * 16;
        GLDS16(sh + so, dst + wv * 1024);
        GLDS16(sl + so, dst + 4096 + wv * 1024);
    };

    i32x4 bAh[2], bAl[2], bBh[2], bBl[2];  // named B sets (rule #20)

#define LOADB(BH, BL, KS)                                                   \
    { _Pragma("unroll")                                                     \
      for (int ksub_ = 0; ksub_ < 2; ++ksub_) {                             \
          int ko_ = ((KS) * 4 + ksub_ * 2 + lk2) * 2048 + boff;             \
          BH[ksub_] = *(const i32x4*)(bWhp + ko_);                          \
          BL[ksub_] = *(const i32x4*)(bWlp + ko_);                          \
      } }

#define COMPUTE(BH, BL, KS)                                                 \
    { char* buf_ = lds + ((KS) & 1) * 8192;                                 \
      __builtin_amdgcn_s_setprio(1);                                        \
      _Pragma("unroll")                                                     \
      for (int ksub_ = 0; ksub_ < 2; ++ksub_) {                             \
          int ao_ = (ksub_ * 2 + lk2) * 1024 + aoff;                        \
          i32x4 ah0 = *(const i32x4*)(buf_ + ao_);                          \
          i32x4 ah1 = *(const i32x4*)(buf_ + ao_ + 512);                    \
          i32x4 al0 = *(const i32x4*)(buf_ + 4096 + ao_);                   \
          i32x4 al1 = *(const i32x4*)(buf_ + 4096 + ao_ + 512);             \
          acc0h = __builtin_amdgcn_mfma_i32_32x32x32_i8(ah0, BH[ksub_], acc0h, 0, 0, 0); \
          acc1h = __builtin_amdgcn_mfma_i32_32x32x32_i8(ah1, BH[ksub_], acc1h, 0, 0, 0); \
          acc0x = __builtin_amdgcn_mfma_i32_32x32x32_i8(ah0, BL[ksub_], acc0x, 0, 0, 0); \
          acc0x = __builtin_amdgcn_mfma_i32_32x32x32_i8(al0, BH[ksub_], acc0x, 0, 0, 0); \
          acc1x = __builtin_amdgcn_mfma_i32_32x32x32_i8(ah1, BL[ksub_], acc1x, 0, 0, 0); \
          acc1x = __builtin_amdgcn_mfma_i32_32x32x32_i8(al1, BH[ksub_], acc1x, 0, 0, 0); \
      }                                                                     \
      __builtin_amdgcn_s_setprio(0); }

    // prologue: glds(0) oldest, then B[0]; vmcnt(4) completes glds(0) only
    stage(0);
    SB0
    LOADB(bAh, bAl, 0)
    SB0
    WAITV4
    BARRAW

#pragma unroll 1
    for (int ks = 0; ks < nkt; ) {
        // even step: consume bA*; prefetch glds(ks+1) then B[ks+1] into bB*
        if (ks + 1 < nkt) { stage(ks + 1); SB0 LOADB(bBh, bBl, ks + 1) }
        SB0
        COMPUTE(bAh, bAl, ks)
        SB0
        WAITV4          // glds(ks+1) done; 4 B[ks+1] remain in flight
        BARRAW
        ++ks;
        if (ks == nkt) break;
        // odd step: consume bB*; prefetch into bA*
        if (ks + 1 < nkt) { stage(ks + 1); SB0 LOADB(bAh, bAl, ks + 1) }
        SB0
        COMPUTE(bBh, bBl, ks)
        SB0
        WAITV4
        BARRAW
        ++ks;
    }
#undef LOADB
#undef COMPUTE
    SB0

    // ---- epilogue: descale -> gt LDS [64][132] f32, fused cell update ----
    float* gt = (float*)lds;
    const int colw = wv * 32 + lrow32;
    const float sb = wsc[n0 + colw];
    const float s1 = sb * 2.44140625e-4f;       // 2^14 / 2^26
    const float s2 = sb * 1.9073486328125e-6f;  // 2^7  / 2^26
#pragma unroll
    for (int rg = 0; rg < 16; ++rg) {
        int row = (rg & 3) + 8 * (rg >> 2) + 4 * lk2;
        gt[row * 132 + colw] = (float)acc0h[rg] * s1 + (float)acc0x[rg] * s2;
        gt[(row + 32) * 132 + colw] = (float)acc1h[rg] * s1 + (float)acc1x[rg] * s2;
    }
    __syncthreads();

    const int n_l = tid & 31;
    const int rb2 = (tid >> 5) * 8;
    const int n_g = (n0 >> 2) + n_l;  // global hidden unit
    const float bf = bias[n_g], bi = bias[HSZ + n_g];
    const float bc = bias[2 * HSZ + n_g], bo = bias[3 * HSZ + n_g];
#pragma unroll
    for (int r = 0; r < 8; ++r) {
        int row = rb2 + r;
        int rg = m0 + row;
        float4 g4 = *(const float4*)&gt[row * 132 + n_l * 4];  // f,i,c,o
        float f = sigmf(g4.x + bf);
        float i_ = sigmf(g4.y + bi);
        float c_ = tanhf_(g4.z + bc);
        float o_ = sigmf(g4.w + bo);
        size_t cidx = (size_t)rg * HSZ + n_g;
        float Cn = f * C[cidx] + i_ * c_;
        C[cidx] = Cn;
        float hv = o_ * tanhf_(Cn);
        int hqv = clamp13(__float2int_rn(hv * 8192.0f));
        int hh8 = (hqv + 64) >> 7;
        int hl8 = hqv - (hh8 << 7);
        size_t hidx = (((size_t)(rg >> 6) * 32 + (n_g >> 4)) * 64 + (rg & 63)) * 16 + (n_g & 15);
        hhi[hidx] = (char)hh8;
        hlo[hidx] = (char)hl8;
    }
}

__device__ __forceinline__ int pack4(int a, int b, int c, int d) {
    return (a & 255) | ((b & 255) << 8) | ((c & 255) << 16) | ((d & 255) << 24);
}

// x[B][T][64] f32 -> x'=x/6 quantized i8 hi/lo in [t][p][kc16(4)][r][16]
__global__ __launch_bounds__(256) void convert_x(const float* __restrict__ x,
                                                 char* __restrict__ xh,
                                                 char* __restrict__ xl)
{
    int gid = blockIdx.x * 256 + threadIdx.x;  // T*16*4*64 = 196608
    int r = gid & 63;
    int kc = (gid >> 6) & 3;
    int pp = (gid >> 8) & 15;
    int t = gid >> 12;
    int b = pp * 64 + r;
    const float* src = x + ((size_t)b * TSZ + t) * INSZ + kc * 16;
    int qh[16], ql[16];
#pragma unroll
    for (int j = 0; j < 16; ++j) {
        int q = clamp13(__float2int_rn(src[j] * (8192.0f / 6.0f)));
        qh[j] = (q + 64) >> 7;
        ql[j] = q - (qh[j] << 7);
    }
    size_t o = ((((size_t)t * 16 + pp) * 4 + kc) * 64 + r) * 16;
    i32x4 ph, pl;
#pragma unroll
    for (int w = 0; w < 4; ++w) {
        ph[w] = pack4(qh[4 * w], qh[4 * w + 1], qh[4 * w + 2], qh[4 * w + 3]);
        pl[w] = pack4(ql[4 * w], ql[4 * w + 1], ql[4 * w + 2], ql[4 * w + 3]);
    }
    *(i32x4*)(xh + o) = ph;
    *(i32x4*)(xl + o) = pl;
}

// per-column' max |W'| (x-rows scaled by xmul). out[col'] = scale.
// grid 8 x 256: thread = source col sc = gate*512+n; out idx = n*4+gate.
__global__ __launch_bounds__(256) void wscale_kernel(
    const float* __restrict__ Wx, const float* __restrict__ Wh,
    int Kx, float xmul, float* __restrict__ out)
{
    int sc = blockIdx.x * 256 + threadIdx.x;
    float m = 1e-8f;
    for (int k = 0; k < Kx; ++k) m = fmaxf(m, fabsf(Wx[(size_t)k * GSZ + sc]) * xmul);
    for (int k = 0; k < HSZ; ++k) m = fmaxf(m, fabsf(Wh[(size_t)k * GSZ + sc]));
    out[(sc & 511) * 4 + (sc >> 9)] = m;
}

// W[k][gate*512+n] f32 -> W' quantized i8 hi/lo [np][kc16][c][16]
// grid (Ktot/64, 16); l0: rows k<kxlim multiplied by xmul before quant.
__global__ __launch_bounds__(256) void convert_w(
    const float* __restrict__ Wx, const float* __restrict__ Wh,
    int Kx, int Ktot, int kxlim, float xmul, const float* __restrict__ wsc,
    char* __restrict__ outh, char* __restrict__ outl)
{
    __shared__ float tile[64][129];
    const int kt = blockIdx.x, np = blockIdx.y;
    const int k0 = kt * 64;
    const float* src;
    int krel;
    if (k0 < Kx) { src = Wx; krel = k0; } else { src = Wh; krel = k0 - Kx; }
#pragma unroll
    for (int i = 0; i < 32; ++i) {
        int idx = threadIdx.x + i * 256;
        int k_l = idx >> 7, gate = (idx >> 5) & 3, n_l = idx & 31;
        float mul = (k0 + k_l < kxlim) ? xmul : 1.0f;
        tile[k_l][n_l * 4 + gate] =
            src[(size_t)(krel + k_l) * GSZ + gate * HSZ + np * 32 + n_l] * mul;
    }
    __syncthreads();
    const size_t obase = ((size_t)np * (Ktot >> 4) + kt * 4) * 2048;
#pragma unroll
    for (int i = 0; i < 32; ++i) {
        int idx = threadIdx.x + i * 256;
        int kcl = idx >> 11, c = (idx >> 4) & 127, e = idx & 15;
        float v = tile[kcl * 16 + e][c];
        float s = wsc[np * 128 + c];
        int q = clamp13(__float2int_rn(v * 8192.0f / s));
        int qh = (q + 64) >> 7;
        int ql = q - (qh << 7);
        outh[obase + idx] = (char)qh;
        outl[obase + idx] = (char)ql;
    }
}

// out[b] = sum_n h[b][n]*w[n] + bias; h from i8 hi/lo pk slabs
__global__ __launch_bounds__(256) void fc_kernel(
    const char* __restrict__ hh, const char* __restrict__ hl,
    const float* __restrict__ w, const float* __restrict__ b,
    float* __restrict__ out)
{
    int wave = (blockIdx.x * 256 + threadIdx.x) >> 6;  // batch row
    int lane = threadIdx.x & 63;
    if (wave >= BSZ) return;
    int pp = wave >> 6, r = wave & 63;
    size_t o = (((size_t)pp * 32 + (lane >> 1)) * 64 + r) * 16 + (lane & 1) * 8;
    char8 vh = *(const char8*)(hh + o);
    char8 vl = *(const char8*)(hl + o);
    float s = 0.0f;
#pragma unroll
    for (int j = 0; j < 8; ++j) {
        int hv = (int)vh[j] * 128 + (int)vl[j];
        s += (float)hv * w[lane * 8 + j];
    }
#pragma unroll
    for (int off = 32; off; off >>= 1) s += __shfl_down(s, off);
    if (lane == 0) out[wave] = s * (1.0f / 8192.0f) + b[0];
}

extern "C" void kernel_launch(void* const* d_in, const int* in_sizes, int n_in,
                              void* d_out, int out_size, void* d_ws, size_t ws_size,
                              hipStream_t stream) {
    const float* x   = (const float*)d_in[0];
    const float* Wx0 = (const float*)d_in[1];
    const float* Wh0 = (const float*)d_in[2];
    const float* b0  = (const float*)d_in[3];
    const float* Wx1 = (const float*)d_in[4];
    const float* Wh1 = (const float*)d_in[5];
    const float* b1  = (const float*)d_in[6];
    const float* Wx2 = (const float*)d_in[7];
    const float* Wh2 = (const float*)d_in[8];
    const float* b2  = (const float*)d_in[9];
    const float* fcw = (const float*)d_in[10];
    const float* fcb = (const float*)d_in[11];

    char* p = (char*)d_ws;
    const size_t hsl = (size_t)BSZ * HSZ;           // 512 KB per i8 h-slab
    char* hq = p; p += 12 * hsl;                    // [par][layer][hilo]
    float* Cbuf = (float*)p; p += 3 * hsl * sizeof(float);
    const size_t zero_bytes = (size_t)(p - (char*)d_ws);

    const size_t xsl = (size_t)TSZ * BSZ * INSZ;    // 3 MB per i8 x-slab
    char* xqh = p; p += xsl;
    char* xql = p; p += xsl;

    const int K0 = INSZ + HSZ;   // 576
    const int K12 = 2 * HSZ;     // 1024
    const size_t w0s = (size_t)GSZ * K0;
    const size_t w12s = (size_t)GSZ * K12;
    char* w0h = p; p += w0s;
    char* w0l = p; p += w0s;
    char* w1h = p; p += w12s;
    char* w1l = p; p += w12s;
    char* w2h = p; p += w12s;
    char* w2l = p; p += w12s;
    float* ws0 = (float*)p; p += GSZ * sizeof(float);
    float* ws1 = (float*)p; p += GSZ * sizeof(float);
    float* ws2 = (float*)p; p += GSZ * sizeof(float);

    hipMemsetAsync(d_ws, 0, zero_bytes, stream);

    wscale_kernel<<<dim3(8), dim3(256), 0, stream>>>(Wx0, Wh0, INSZ, 6.0f, ws0);
    wscale_kernel<<<dim3(8), dim3(256), 0, stream>>>(Wx1, Wh1, HSZ, 1.0f, ws1);
    wscale_kernel<<<dim3(8), dim3(256), 0, stream>>>(Wx2, Wh2, HSZ, 1.0f, ws2);
    convert_w<<<dim3(K0 / 64, 16), dim3(256), 0, stream>>>(Wx0, Wh0, INSZ, K0, 64, 6.0f, ws0, w0h, w0l);
    convert_w<<<dim3(K12 / 64, 16), dim3(256), 0, stream>>>(Wx1, Wh1, HSZ, K12, 0, 1.0f, ws1, w1h, w1l);
    convert_w<<<dim3(K12 / 64, 16), dim3(256), 0, stream>>>(Wx2, Wh2, HSZ, K12, 0, 1.0f, ws2, w2h, w2l);
    convert_x<<<dim3(TSZ * BSZ * INSZ / 16 / 256), dim3(256), 0, stream>>>(x, xqh, xql);

    // diagonal wavefront: d = t + l, cells (t,l) with t+l == d are independent
    for (int dgn = 0; dgn < TSZ + 2; ++dgn) {
        int lmin = (dgn - (TSZ - 1)) > 0 ? (dgn - (TSZ - 1)) : 0;
        int lmax = dgn < 2 ? dgn : 2;
        int ncells = lmax - lmin + 1;
        lstm_diag<<<dim3(16, 16, ncells), dim3(256), 0, stream>>>(
            xqh, xql, hq, Cbuf,
            w0h, w0l, w1h, w1l, w2h, w2l,
            ws0, ws1, ws2, b0, b1, b2, dgn, lmin);
    }

    // h of layer 2 at t=47 lives at parity 47&1 = 1
    char* h2h = hq + (((size_t)1 * 3 + 2) * 2 + 0) * hsl;
    char* h2l = hq + (((size_t)1 * 3 + 2) * 2 + 1) * hsl;
    fc_kernel<<<dim3(BSZ / 4), dim3(256), 0, stream>>>(h2h, h2l, fcw, fcb, (float*)d_out);
}

// Round 16
// 2464.988 us; speedup vs baseline: 1.1846x; 1.1846x over previous
//
#include <hip/hip_runtime.h>
#include <hip/hip_bf16.h>
#include <stdint.h>

#define BSZ 1024
#define HSZ 512
#define TSZ 48
#define INSZ 64
#define GSZ 2048  // 4*HSZ

typedef __attribute__((ext_vector_type(4))) int i32x4;
typedef __attribute__((ext_vector_type(16))) int i32x16;
typedef __attribute__((ext_vector_type(8))) char char8;

#define GLDS16(g, l)                                                        \
    __builtin_amdgcn_global_load_lds(                                       \
        (const __attribute__((address_space(1))) void*)(g),                 \
        (__attribute__((address_space(3))) void*)(l), 16, 0, 0)

#define SB0 __builtin_amdgcn_sched_barrier(0);
#define WAITV4 asm volatile("s_waitcnt vmcnt(4)" ::: "memory");
#define BARRAW __builtin_amdgcn_s_barrier();

__device__ __forceinline__ float sigmf(float x) { return 1.0f / (1.0f + __expf(-x)); }
__device__ __forceinline__ float tanhf_(float x) { return 2.0f / (1.0f + __expf(-2.0f * x)) - 1.0f; }
__device__ __forceinline__ int clamp13(int q) {
    return q > 8191 ? 8191 : (q < -8191 ? -8191 : q);
}

// ---- i8 fixed-point scheme ----
// A (h, or x/6) in (-1,1): aq = rn(a*8192) 14-bit; ah=(aq+64)>>7, al=aq-(ah<<7).
// W': l0 x-rows pre-multiplied by 6; per-column scale sB; bq = rn(w/sB*8192).
// a.b = sB*2^-26 * (2^14*ACC_hh + 2^7*ACC_x),  ACC_x = sum(ah*bl + al*bh).
// (al*bl dropped, rel err ~2e-4.)  [VALIDATED r15: absmax 4.88e-4]
// Layouts (i8, hi/lo separate slabs, 16-elem k-chunks):
//   A: [p=row/64][kc16=k/16][r=row&63][e=16]   W: [np=col'/128][kc16][c=col'&127][e=16]
// col' = hidden*4 + gate. MFMA i32_32x32x32_i8 (K=32, 2x bf16 rate, exact).
// Skeleton = r12: A->LDS dbuf via glds, B->reg dbuf (named sets), counted
// vmcnt(4) + raw barrier (glds completes, B stays in flight).
// grid (16,16,ncells): 64 rows x 128 gate-cols per block, 256 threads.
__global__ __launch_bounds__(256, 3) void lstm_diag(
    const char* __restrict__ xqh, const char* __restrict__ xql,
    char* __restrict__ hq,          // [par][layer][hilo] i8 pk-slabs
    float* __restrict__ Cbuf,       // [layer][B*H] f32
    const char* __restrict__ W0h, const char* __restrict__ W0l,
    const char* __restrict__ W1h, const char* __restrict__ W1l,
    const char* __restrict__ W2h, const char* __restrict__ W2l,
    const float* __restrict__ ws0, const float* __restrict__ ws1,
    const float* __restrict__ ws2,
    const float* __restrict__ b0, const float* __restrict__ b1,
    const float* __restrict__ b2,
    int d, int lmin)
{
    // A dbuf: 2 x (hi 4K | lo 4K) = 16K; epilogue gt 64*132*4 = 33792 (aliased)
    __shared__ __align__(16) char lds[33792];

    const int l = lmin + blockIdx.z;
    const int t = d - l;
    const size_t hsl = (size_t)BSZ * HSZ;  // bytes per i8 h-slab
    auto Hq = [&](int par, int ll, int hilo) {
        return hq + (((size_t)par * 3 + ll) * 2 + hilo) * hsl;
    };

    const char* Wph = (l == 0) ? W0h : (l == 1) ? W1h : W2h;
    const char* Wpl = (l == 0) ? W0l : (l == 1) ? W1l : W2l;
    const float* wsc = (l == 0) ? ws0 : (l == 1) ? ws1 : ws2;
    const float* bias = (l == 0) ? b0 : (l == 1) ? b1 : b2;
    const int Kx    = (l == 0) ? INSZ : HSZ;
    const int KCa16 = Kx >> 4;        // kc16 per panel in x-source slab (4 / 32)
    const int Ktot  = Kx + HSZ;
    const int KCt16 = Ktot >> 4;
    const int nkx   = Kx >> 6;        // ksteps in x phase (1 or 8)
    const int nkt   = Ktot >> 6;      // total ksteps (9 or 16)
    const int cur = t & 1, prv = cur ^ 1;
    const char* Axh = (l == 0) ? xqh + (size_t)t * 65536 : Hq(cur, l - 1, 0);
    const char* Axl = (l == 0) ? xql + (size_t)t * 65536 : Hq(cur, l - 1, 1);
    const char* Ahh = Hq(prv, l, 0);
    const char* Ahl = Hq(prv, l, 1);
    float* C = Cbuf + (size_t)l * BSZ * HSZ;
    char* hhi = Hq(cur, l, 0);
    char* hlo = Hq(cur, l, 1);

    // XCD-aware bijective swizzle within the 256-block z-slice (256 % 8 == 0).
    const int bid = blockIdx.x + (blockIdx.y << 4);
    const int swz = (bid & 7) * 32 + (bid >> 3);
    const int m0 = (swz & 15) * 64;
    const int n0 = (swz >> 4) * 128;
    const int p  = swz & 15;    // A row-panel
    const int np = swz >> 4;    // W col-panel

    const int tid = threadIdx.x;
    const int lane = tid & 63;
    const int wv = tid >> 6;
    const int lrow32 = lane & 31;
    const int lk2 = lane >> 5;

    // A source byte bases (panel-resolved)
    const char* bAxh = Axh + (size_t)p * KCa16 * 1024;
    const char* bAxl = Axl + (size_t)p * KCa16 * 1024;
    const char* bAhh = Ahh + (size_t)p * 32 * 1024;
    const char* bAhl = Ahl + (size_t)p * 32 * 1024;
    // W byte bases (panel-resolved)
    const char* bWhp = Wph + (size_t)np * KCt16 * 2048;
    const char* bWlp = Wpl + (size_t)np * KCt16 * 2048;

    // per-lane offsets
    const int boff = (wv * 32 + lrow32) * 16;   // + kc16*2048
    const int aoff = lrow32 * 16;               // + kc16*1024 (+512 rows 32-63)

    i32x16 acc0h, acc0x, acc1h, acc1x;
#pragma unroll
    for (int r = 0; r < 16; ++r) { acc0h[r] = 0; acc0x[r] = 0; acc1h[r] = 0; acc1x[r] = 0; }

    // stage A kstep ks into buf[ks&1]: 8 x 1KB segments (4 hi + 4 lo), 2/wave
    auto stage = [&](int ks) {
        const char *sh, *sl;
        int kc0;
        if (ks < nkx) { sh = bAxh; sl = bAxl; kc0 = ks * 4; }
        else          { sh = bAhh; sl = bAhl; kc0 = (ks - nkx) * 4; }
        char* dst = lds + (ks & 1) * 8192;
        size_t so = (size_t)(kc0 + wv) * 1024 + lane * 16;
        GLDS16(sh + so, dst + wv * 1024);
        GLDS16(sl + so, dst + 4096 + wv * 1024);
    };

    i32x4 bAh[2], bAl[2], bBh[2], bBl[2];  // named B sets (rule #20)

#define LOADB(BH, BL, KS)                                                   \
    { _Pragma("unroll")                                                     \
      for (int ksub_ = 0; ksub_ < 2; ++ksub_) {                             \
          int ko_ = ((KS) * 4 + ksub_ * 2 + lk2) * 2048 + boff;             \
          BH[ksub_] = *(const i32x4*)(bWhp + ko_);                          \
          BL[ksub_] = *(const i32x4*)(bWlp + ko_);                          \
      } }

#define COMPUTE(BH, BL, KS)                                                 \
    { char* buf_ = lds + ((KS) & 1) * 8192;                                 \
      __builtin_amdgcn_s_setprio(1);                                        \
      _Pragma("unroll")                                                     \
      for (int ksub_ = 0; ksub_ < 2; ++ksub_) {                             \
          int ao_ = (ksub_ * 2 + lk2) * 1024 + aoff;                        \
          i32x4 ah0 = *(const i32x4*)(buf_ + ao_);                          \
          i32x4 ah1 = *(const i32x4*)(buf_ + ao_ + 512);                    \
          i32x4 al0 = *(const i32x4*)(buf_ + 4096 + ao_);                   \
          i32x4 al1 = *(const i32x4*)(buf_ + 4096 + ao_ + 512);             \
          acc0h = __builtin_amdgcn_mfma_i32_32x32x32_i8(ah0, BH[ksub_], acc0h, 0, 0, 0); \
          acc1h = __builtin_amdgcn_mfma_i32_32x32x32_i8(ah1, BH[ksub_], acc1h, 0, 0, 0); \
          acc0x = __builtin_amdgcn_mfma_i32_32x32x32_i8(ah0, BL[ksub_], acc0x, 0, 0, 0); \
          acc0x = __builtin_amdgcn_mfma_i32_32x32x32_i8(al0, BH[ksub_], acc0x, 0, 0, 0); \
          acc1x = __builtin_amdgcn_mfma_i32_32x32x32_i8(ah1, BL[ksub_], acc1x, 0, 0, 0); \
          acc1x = __builtin_amdgcn_mfma_i32_32x32x32_i8(al1, BH[ksub_], acc1x, 0, 0, 0); \
      }                                                                     \
      __builtin_amdgcn_s_setprio(0); }

    // prologue: glds(0) oldest, then B[0]; vmcnt(4) completes glds(0) only
    stage(0);
    SB0
    LOADB(bAh, bAl, 0)
    SB0
    WAITV4
    BARRAW

#pragma unroll 1
    for (int ks = 0; ks < nkt; ) {
        // even step: consume bA*; prefetch glds(ks+1) then B[ks+1] into bB*
        if (ks + 1 < nkt) { stage(ks + 1); SB0 LOADB(bBh, bBl, ks + 1) }
        SB0
        COMPUTE(bAh, bAl, ks)
        SB0
        WAITV4          // glds(ks+1) done; 4 B[ks+1] remain in flight
        BARRAW
        ++ks;
        if (ks == nkt) break;
        // odd step: consume bB*; prefetch into bA*
        if (ks + 1 < nkt) { stage(ks + 1); SB0 LOADB(bAh, bAl, ks + 1) }
        SB0
        COMPUTE(bBh, bBl, ks)
        SB0
        WAITV4
        BARRAW
        ++ks;
    }
#undef LOADB
#undef COMPUTE
    SB0

    // ---- epilogue: descale -> gt LDS [64][132] f32, fused cell update ----
    float* gt = (float*)lds;
    const int colw = wv * 32 + lrow32;
    const float sb = wsc[n0 + colw];
    const float s1 = sb * 2.44140625e-4f;       // 2^14 / 2^26
    const float s2 = sb * 1.9073486328125e-6f;  // 2^7  / 2^26
#pragma unroll
    for (int rg = 0; rg < 16; ++rg) {
        int row = (rg & 3) + 8 * (rg >> 2) + 4 * lk2;
        gt[row * 132 + colw] = (float)acc0h[rg] * s1 + (float)acc0x[rg] * s2;
        gt[(row + 32) * 132 + colw] = (float)acc1h[rg] * s1 + (float)acc1x[rg] * s2;
    }
    __syncthreads();

    const int n_l = tid & 31;
    const int rb2 = (tid >> 5) * 8;
    const int n_g = (n0 >> 2) + n_l;  // global hidden unit
    const float bf = bias[n_g], bi = bias[HSZ + n_g];
    const float bc = bias[2 * HSZ + n_g], bo = bias[3 * HSZ + n_g];
#pragma unroll
    for (int r = 0; r < 8; ++r) {
        int row = rb2 + r;
        int rg = m0 + row;
        float4 g4 = *(const float4*)&gt[row * 132 + n_l * 4];  // f,i,c,o
        float f = sigmf(g4.x + bf);
        float i_ = sigmf(g4.y + bi);
        float c_ = tanhf_(g4.z + bc);
        float o_ = sigmf(g4.w + bo);
        size_t cidx = (size_t)rg * HSZ + n_g;
        float Cn = f * C[cidx] + i_ * c_;
        C[cidx] = Cn;
        float hv = o_ * tanhf_(Cn);
        int hqv = clamp13(__float2int_rn(hv * 8192.0f));
        int hh8 = (hqv + 64) >> 7;
        int hl8 = hqv - (hh8 << 7);
        size_t hidx = (((size_t)(rg >> 6) * 32 + (n_g >> 4)) * 64 + (rg & 63)) * 16 + (n_g & 15);
        hhi[hidx] = (char)hh8;
        hlo[hidx] = (char)hl8;
    }
}

__device__ __forceinline__ int pack4(int a, int b, int c, int d) {
    return (a & 255) | ((b & 255) << 8) | ((c & 255) << 16) | ((d & 255) << 24);
}

// x[B][T][64] f32 -> x'=x/6 quantized i8 hi/lo in [t][p][kc16(4)][r][16]
__global__ __launch_bounds__(256) void convert_x(const float* __restrict__ x,
                                                 char* __restrict__ xh,
                                                 char* __restrict__ xl)
{
    int gid = blockIdx.x * 256 + threadIdx.x;  // T*16*4*64 = 196608
    int r = gid & 63;
    int kc = (gid >> 6) & 3;
    int pp = (gid >> 8) & 15;
    int t = gid >> 12;
    int b = pp * 64 + r;
    const float* src = x + ((size_t)b * TSZ + t) * INSZ + kc * 16;
    int qh[16], ql[16];
#pragma unroll
    for (int j = 0; j < 16; ++j) {
        int q = clamp13(__float2int_rn(src[j] * (8192.0f / 6.0f)));
        qh[j] = (q + 64) >> 7;
        ql[j] = q - (qh[j] << 7);
    }
    size_t o = ((((size_t)t * 16 + pp) * 4 + kc) * 64 + r) * 16;
    i32x4 ph, pl;
#pragma unroll
    for (int w = 0; w < 4; ++w) {
        ph[w] = pack4(qh[4 * w], qh[4 * w + 1], qh[4 * w + 2], qh[4 * w + 3]);
        pl[w] = pack4(ql[4 * w], ql[4 * w + 1], ql[4 * w + 2], ql[4 * w + 3]);
    }
    *(i32x4*)(xh + o) = ph;
    *(i32x4*)(xl + o) = pl;
}

// Parallel per-column' |W'| max via atomicMax on positive-float bit pattern
// (monotone for non-negative floats; bit-max is order-independent ->
// deterministic). out must be ZEROED before launch (memset region).
// grid (Ktot/64, 8): block = (kchunk, colchunk); thread = one source col,
// 64 coalesced rows; one atomic per thread.
__global__ __launch_bounds__(256) void wscale_kernel(
    const float* __restrict__ Wx, const float* __restrict__ Wh,
    int Kx, float xmul, float* __restrict__ out)
{
    int sc = blockIdx.y * 256 + threadIdx.x;  // source col = gate*512+n
    int k0 = blockIdx.x * 64;
    const float* src;
    int krel;
    float mul;
    if (k0 < Kx) { src = Wx; krel = k0; mul = xmul; }   // Kx is a multiple of 64
    else         { src = Wh; krel = k0 - Kx; mul = 1.0f; }
    float m = 0.0f;
#pragma unroll 8
    for (int k = 0; k < 64; ++k)
        m = fmaxf(m, fabsf(src[(size_t)(krel + k) * GSZ + sc]));
    m *= mul;
    atomicMax((int*)&out[(sc & 511) * 4 + (sc >> 9)], __float_as_int(m));
}

// W[k][gate*512+n] f32 -> W' quantized i8 hi/lo [np][kc16][c][16]
// grid (Ktot/64, 16); l0: rows k<kxlim multiplied by xmul before quant.
__global__ __launch_bounds__(256) void convert_w(
    const float* __restrict__ Wx, const float* __restrict__ Wh,
    int Kx, int Ktot, int kxlim, float xmul, const float* __restrict__ wsc,
    char* __restrict__ outh, char* __restrict__ outl)
{
    __shared__ float tile[64][129];
    const int kt = blockIdx.x, np = blockIdx.y;
    const int k0 = kt * 64;
    const float* src;
    int krel;
    if (k0 < Kx) { src = Wx; krel = k0; } else { src = Wh; krel = k0 - Kx; }
#pragma unroll
    for (int i = 0; i < 32; ++i) {
        int idx = threadIdx.x + i * 256;
        int k_l = idx >> 7, gate = (idx >> 5) & 3, n_l = idx & 31;
        float mul = (k0 + k_l < kxlim) ? xmul : 1.0f;
        tile[k_l][n_l * 4 + gate] =
            src[(size_t)(krel + k_l) * GSZ + gate * HSZ + np * 32 + n_l] * mul;
    }
    __syncthreads();
    const size_t obase = ((size_t)np * (Ktot >> 4) + kt * 4) * 2048;
#pragma unroll
    for (int i = 0; i < 32; ++i) {
        int idx = threadIdx.x + i * 256;
        int kcl = idx >> 11, c = (idx >> 4) & 127, e = idx & 15;
        float v = tile[kcl * 16 + e][c];
        float s = fmaxf(wsc[np * 128 + c], 1e-30f);
        int q = clamp13(__float2int_rn(v * 8192.0f / s));
        int qh = (q + 64) >> 7;
        int ql = q - (qh << 7);
        outh[obase + idx] = (char)qh;
        outl[obase + idx] = (char)ql;
    }
}

// out[b] = sum_n h[b][n]*w[n] + bias; h from i8 hi/lo pk slabs
__global__ __launch_bounds__(256) void fc_kernel(
    const char* __restrict__ hh, const char* __restrict__ hl,
    const float* __restrict__ w, const float* __restrict__ b,
    float* __restrict__ out)
{
    int wave = (blockIdx.x * 256 + threadIdx.x) >> 6;  // batch row
    int lane = threadIdx.x & 63;
    if (wave >= BSZ) return;
    int pp = wave >> 6, r = wave & 63;
    size_t o = (((size_t)pp * 32 + (lane >> 1)) * 64 + r) * 16 + (lane & 1) * 8;
    char8 vh = *(const char8*)(hh + o);
    char8 vl = *(const char8*)(hl + o);
    float s = 0.0f;
#pragma unroll
    for (int j = 0; j < 8; ++j) {
        int hv = (int)vh[j] * 128 + (int)vl[j];
        s += (float)hv * w[lane * 8 + j];
    }
#pragma unroll
    for (int off = 32; off; off >>= 1) s += __shfl_down(s, off);
    if (lane == 0) out[wave] = s * (1.0f / 8192.0f) + b[0];
}

extern "C" void kernel_launch(void* const* d_in, const int* in_sizes, int n_in,
                              void* d_out, int out_size, void* d_ws, size_t ws_size,
                              hipStream_t stream) {
    const float* x   = (const float*)d_in[0];
    const float* Wx0 = (const float*)d_in[1];
    const float* Wh0 = (const float*)d_in[2];
    const float* b0  = (const float*)d_in[3];
    const float* Wx1 = (const float*)d_in[4];
    const float* Wh1 = (const float*)d_in[5];
    const float* b1  = (const float*)d_in[6];
    const float* Wx2 = (const float*)d_in[7];
    const float* Wh2 = (const float*)d_in[8];
    const float* b2  = (const float*)d_in[9];
    const float* fcw = (const float*)d_in[10];
    const float* fcb = (const float*)d_in[11];

    char* p = (char*)d_ws;
    const size_t hsl = (size_t)BSZ * HSZ;           // 512 KB per i8 h-slab
    char* hq = p; p += 12 * hsl;                    // [par][layer][hilo]
    float* Cbuf = (float*)p; p += 3 * hsl * sizeof(float);
    float* ws0 = (float*)p; p += GSZ * sizeof(float);   // in memset region
    float* ws1 = (float*)p; p += GSZ * sizeof(float);   // (atomicMax identity
    float* ws2 = (float*)p; p += GSZ * sizeof(float);   //  = 0x0 = 0.0f)
    const size_t zero_bytes = (size_t)(p - (char*)d_ws);

    const size_t xsl = (size_t)TSZ * BSZ * INSZ;    // 3 MB per i8 x-slab
    char* xqh = p; p += xsl;
    char* xql = p; p += xsl;

    const int K0 = INSZ + HSZ;   // 576
    const int K12 = 2 * HSZ;     // 1024
    const size_t w0s = (size_t)GSZ * K0;
    const size_t w12s = (size_t)GSZ * K12;
    char* w0h = p; p += w0s;
    char* w0l = p; p += w0s;
    char* w1h = p; p += w12s;
    char* w1l = p; p += w12s;
    char* w2h = p; p += w12s;
    char* w2l = p; p += w12s;

    hipMemsetAsync(d_ws, 0, zero_bytes, stream);

    wscale_kernel<<<dim3(K0 / 64, 8), dim3(256), 0, stream>>>(Wx0, Wh0, INSZ, 6.0f, ws0);
    wscale_kernel<<<dim3(K12 / 64, 8), dim3(256), 0, stream>>>(Wx1, Wh1, HSZ, 1.0f, ws1);
    wscale_kernel<<<dim3(K12 / 64, 8), dim3(256), 0, stream>>>(Wx2, Wh2, HSZ, 1.0f, ws2);
    convert_w<<<dim3(K0 / 64, 16), dim3(256), 0, stream>>>(Wx0, Wh0, INSZ, K0, 64, 6.0f, ws0, w0h, w0l);
    convert_w<<<dim3(K12 / 64, 16), dim3(256), 0, stream>>>(Wx1, Wh1, HSZ, K12, 0, 1.0f, ws1, w1h, w1l);
    convert_w<<<dim3(K12 / 64, 16), dim3(256), 0, stream>>>(Wx2, Wh2, HSZ, K12, 0, 1.0f, ws2, w2h, w2l);
    convert_x<<<dim3(TSZ * BSZ * INSZ / 16 / 256), dim3(256), 0, stream>>>(x, xqh, xql);

    // diagonal wavefront: d = t + l, cells (t,l) with t+l == d are independent
    for (int dgn = 0; dgn < TSZ + 2; ++dgn) {
        int lmin = (dgn - (TSZ - 1)) > 0 ? (dgn - (TSZ - 1)) : 0;
        int lmax = dgn < 2 ? dgn : 2;
        int ncells = lmax - lmin + 1;
        lstm_diag<<<dim3(16, 16, ncells), dim3(256), 0, stream>>>(
            xqh, xql, hq, Cbuf,
            w0h, w0l, w1h, w1l, w2h, w2l,
            ws0, ws1, ws2, b0, b1, b2, dgn, lmin);
    }

    // h of layer 2 at t=47 lives at parity 47&1 = 1
    char* h2h = hq + (((size_t)1 * 3 + 2) * 2 + 0) * hsl;
    char* h2l = hq + (((size_t)1 * 3 + 2) * 2 + 1) * hsl;
    fc_kernel<<<dim3(BSZ / 4), dim3(256), 0, stream>>>(h2h, h2l, fcw, fcb, (float*)d_out);
}